// Round 3
// baseline (47.025 us; speedup 1.0000x reference)
//
#include <hip/hip_runtime.h>

#define WIN_SIZE   400
#define WIN_SHIFT  160
#define BATCH      32
#define T_LEN      480000
#define NFRAMES    2998                  // (480000-400)/160 + 1
#define FTILE      64
#define NTILES     47                    // ceil(2998/64)
#define NBLOCKS    (NTILES * BATCH)      // 1504 = 8 * 188
#define PER_XCD    (NBLOCKS / 8)         // 188 = 4 whole batches of 47 tiles
#define TILE_SAMP  (FTILE * WIN_SHIFT)   // 10240
// ownership phase-shift: tile k owns frames [64k+phi(w), 64k+64+phi(w)),
// phi(w) = (-6w) mod 16 (even, <=14)  ->  store base 64B-aligned, 4 full lines.
// staged frames per tile: [64k, 64k+77]  ->  77*160+400 = 12720 samples.
#define SAMPLES_EXT (77 * WIN_SHIFT + WIN_SIZE)   // 12720
#define LX_PAD      12752                // swz(a) <= a+31
#define TAIL_FRAMES (NFRAMES - FTILE * (NTILES - 1))   // 54

// XOR-swizzle: compute reads are stride-160 (5*32 banks) -> 32-way conflict
// unswizzled. bank(swz(C+160l)) = (C&31) ^ ((C>>5 + 5l)&31); 5 coprime 32 ->
// 2-way over 64 lanes (free, m136).
__device__ __forceinline__ int swz(int a) { return a ^ ((a >> 5) & 31); }

__global__ __launch_bounds__(256) void window_frame_kernel(
    const float* __restrict__ x, const float* __restrict__ window,
    float* __restrict__ out)
{
    __shared__ float lx[LX_PAD];
    __shared__ float lw[WIN_SIZE];

    // XCD-aware bijective swizzle: each XCD owns 188 consecutive (b,tile) ids
    // = 4 whole batches -> neighbor tiles share an L2 (read-overlap reuse).
    const int flat = blockIdx.x;
    const int lin  = (flat & 7) * PER_XCD + (flat >> 3);
    const int b    = lin / NTILES;
    const int k    = lin % NTILES;

    const long base  = (long)b * T_LEN + (long)k * TILE_SAMP;
    const int  avail = T_LEN - k * TILE_SAMP;       // multiple of 16
    const int  need  = min(SAMPLES_EXT, avail);
    const int  need4 = need >> 2;

    const int tid = threadIdx.x;

    for (int i = tid; i < WIN_SIZE; i += 256) lw[i] = window[i];

    // stage x: coalesced float4 loads -> swizzled scalar LDS writes (<=2-way)
    const float4* __restrict__ xg = (const float4*)(x + base);
    for (int i4 = tid; i4 < need4; i4 += 256) {
        float4 v = xg[i4];
        int a = i4 << 2;
        lx[swz(a + 0)] = v.x;
        lx[swz(a + 1)] = v.y;
        lx[swz(a + 2)] = v.z;
        lx[swz(a + 3)] = v.w;
    }
    __syncthreads();

    const int lane = tid & 63;
    const int wid  = tid >> 6;
    const long rstride = 4L * NFRAMES;

    if (k < NTILES - 1) {
        // interior tiles: exactly 64 frames per row, line-aligned store base
        float* __restrict__ orow =
            out + ((long)(b * WIN_SIZE + wid)) * NFRAMES + FTILE * k;
        for (int w = wid; w < WIN_SIZE; w += 4) {
            const int phi = (-6 * w) & 15;
            orow[phi + lane] = lx[swz(160 * (phi + lane) + w)] * lw[w];
            orow += rstride;
        }
        if (k == 0) {   // head: frames [0, phi) of each row
            float* __restrict__ oh =
                out + ((long)(b * WIN_SIZE + wid)) * NFRAMES;
            for (int w = wid; w < WIN_SIZE; w += 4) {
                const int phi = (-6 * w) & 15;
                if (lane < phi)
                    oh[lane] = lx[swz(160 * lane + w)] * lw[w];
                oh += rstride;
            }
        }
    } else {
        // last tile: frames [64k+phi, 2998) -> 54-phi lanes active
        float* __restrict__ orow =
            out + ((long)(b * WIN_SIZE + wid)) * NFRAMES + FTILE * k;
        for (int w = wid; w < WIN_SIZE; w += 4) {
            const int phi = (-6 * w) & 15;
            if (lane < TAIL_FRAMES - phi)
                orow[phi + lane] = lx[swz(160 * (phi + lane) + w)] * lw[w];
            orow += rstride;
        }
    }
}

extern "C" void kernel_launch(void* const* d_in, const int* in_sizes, int n_in,
                              void* d_out, int out_size, void* d_ws, size_t ws_size,
                              hipStream_t stream) {
    const float* x      = (const float*)d_in[0];
    const float* window = (const float*)d_in[1];
    // d_in[2] = win_shift scalar (160) — compile-time constant here
    float* out = (float*)d_out;

    window_frame_kernel<<<NBLOCKS, 256, 0, stream>>>(x, window, out);
}

// Round 4
// 40.624 us; speedup vs baseline: 1.1576x; 1.1576x over previous
//
#include <hip/hip_runtime.h>

#define WIN_SIZE   400
#define WIN_SHIFT  160
#define BATCH      32
#define T_LEN      480000
#define NFRAMES    2998                   // (480000-400)/160 + 1
#define FTILE      32
#define NTILES     94                     // 93 full tiles + 22-frame tail
#define NBLOCKS    (NTILES * BATCH)       // 3008 = 8 * 376
#define PER_XCD    (NBLOCKS / 8)          // 376 = 4 whole batches of 94 tiles
#define TILE_SAMP  (FTILE * WIN_SHIFT)    // 5120
#define SAMPLES    ((FTILE-1)*WIN_SHIFT + WIN_SIZE)   // 5360
#define LX_PAD     5392                   // swz(a) <= a+31

// XOR-swizzle: compute reads are stride-160 (5*32 banks) -> 32-way conflict
// unswizzled. bank(swz(160f+w)) = (w&31) ^ ((5f + (w>>5))&31); 5 coprime 32
// -> f=0..31 hits 32 distinct banks; two row-halves -> 2 lanes/bank = free.
__device__ __forceinline__ int swz(int a) { return a ^ ((a >> 5) & 31); }

// FTILE=32: LDS = 5392+400 floats ~ 23 KB -> 6 blocks/CU = 24 waves/CU
// (2x the FTILE=64 version; occupancy was the R2 limiter hypothesis).
__global__ __launch_bounds__(256) void window_frame_kernel(
    const float* __restrict__ x, const float* __restrict__ window,
    float* __restrict__ out)
{
    __shared__ float lx[LX_PAD];
    __shared__ float lw[WIN_SIZE];

    // XCD-aware bijective swizzle: each XCD owns 376 consecutive (b,tile) ids
    // = 4 whole batches -> neighbor tiles share an L2 (overlap reads + line merge)
    const int flat = blockIdx.x;
    const int lin  = (flat & 7) * PER_XCD + (flat >> 3);
    const int b    = lin / NTILES;
    const int k    = lin % NTILES;

    const long base  = (long)b * T_LEN + (long)k * TILE_SAMP;
    const int  avail = T_LEN - k * TILE_SAMP;   // multiple of 16
    const int  need  = min(SAMPLES, avail);
    const int  need4 = need >> 2;

    const int tid = threadIdx.x;

    for (int i = tid; i < WIN_SIZE; i += 256) lw[i] = window[i];

    // stage x: coalesced float4 loads -> swizzled scalar LDS writes
    const float4* __restrict__ xg = (const float4*)(x + base);
    for (int i4 = tid; i4 < need4; i4 += 256) {
        float4 v = xg[i4];
        int a = i4 << 2;
        lx[swz(a + 0)] = v.x;
        lx[swz(a + 1)] = v.y;
        lx[swz(a + 2)] = v.z;
        lx[swz(a + 3)] = v.w;
    }
    __syncthreads();

    const int lane = tid & 63;
    const int wid  = tid >> 6;
    const int f    = lane & 31;          // frame offset within tile
    const int half = lane >> 5;          // which row of the wave's row-pair
    const int fr   = FTILE * k + f;
    const bool ok  = fr < NFRAMES;       // tail tile: 22 frames only
    const int w0   = wid * 2 + half;

    float* __restrict__ op = out + ((long)b * WIN_SIZE + w0) * NFRAMES + fr;
    const int abase = f * WIN_SHIFT;

    // wave handles rows {w0, w0+1} x 32 frames per iter; 50 iters.
    // store: 2 contiguous 128 B segments per wave instruction.
    #pragma unroll 5
    for (int w = w0; w < WIN_SIZE; w += 8) {
        float v = lx[swz(abase + w)] * lw[w];
        if (ok) *op = v;
        op += 8L * NFRAMES;
    }
}

extern "C" void kernel_launch(void* const* d_in, const int* in_sizes, int n_in,
                              void* d_out, int out_size, void* d_ws, size_t ws_size,
                              hipStream_t stream) {
    const float* x      = (const float*)d_in[0];
    const float* window = (const float*)d_in[1];
    // d_in[2] = win_shift scalar (160) — compile-time constant here
    float* out = (float*)d_out;

    window_frame_kernel<<<NBLOCKS, 256, 0, stream>>>(x, window, out);
}

// Round 5
// 39.056 us; speedup vs baseline: 1.2040x; 1.0401x over previous
//
#include <hip/hip_runtime.h>

#define WIN_SIZE   400
#define WIN_SHIFT  160
#define BATCH      32
#define T_LEN      480000
#define NFRAMES    2998                  // (480000-400)/160 + 1
#define FTILE      64
#define NTILES     47                    // ceil(2998/64)
#define NBLOCKS    (NTILES * BATCH)      // 1504 = 8 * 188
#define PER_XCD    (NBLOCKS / 8)         // 188 = 4 whole batches of 47 tiles
#define SAMPLES    ((FTILE-1)*WIN_SHIFT + WIN_SIZE)   // 10480
#define SAMPLES_PAD 10496

// XOR-swizzle: stride-160 (== 5*32 banks) reads would be 32-way conflicted.
// Compute reads a = 320*k2 + 160*j + w + r:
//   bank = ((160j+w+r)&31) ^ ((10*k2 + c)&31); gcd(10,32)=2 -> 16 banks x2
//   per row-half; r=0/1 separate via bit0 -> 2 lanes/bank = free (m136).
__device__ __forceinline__ int swz(int a) { return a ^ ((a >> 5) & 31); }

__global__ __launch_bounds__(256) void window_frame_kernel(
    const float* __restrict__ x, const float* __restrict__ window,
    float* __restrict__ out)
{
    __shared__ float lx[SAMPLES_PAD];
    __shared__ float lw[WIN_SIZE];

    // XCD-aware bijective swizzle: each XCD owns 188 consecutive (b,tile) ids
    // = 4 whole batches -> neighbor tiles share an L2.
    const int flat = blockIdx.x;
    const int lin  = (flat & 7) * PER_XCD + (flat >> 3);
    const int b    = lin / NTILES;
    const int k    = lin % NTILES;

    const long base  = (long)b * T_LEN + (long)k * FTILE * WIN_SHIFT;
    const int  avail = T_LEN - k * FTILE * WIN_SHIFT;    // multiple of 16
    const int  need  = min(SAMPLES, avail);
    const int  need4 = need >> 2;

    const int tid = threadIdx.x;

    for (int i = tid; i < WIN_SIZE; i += 256) lw[i] = window[i];

    // stage x: coalesced float4 loads -> swizzled scalar LDS writes
    const float4* __restrict__ xg = (const float4*)(x + base);
    for (int i4 = tid; i4 < need4; i4 += 256) {
        float4 v = xg[i4];
        int a = i4 << 2;
        lx[swz(a + 0)] = v.x;
        lx[swz(a + 1)] = v.y;
        lx[swz(a + 2)] = v.z;
        lx[swz(a + 3)] = v.w;
    }
    __syncthreads();

    const int lane = tid & 63;
    const int wid  = tid >> 6;
    const int k2   = lane & 31;          // frame-pair index: frames 2k2, 2k2+1
    const int r    = lane >> 5;          // row offset within wave's row-pair
    const int fr   = FTILE * k + 2 * k2;
    const bool ok  = fr < NFRAMES;       // tail tile: 54 frames = 27 whole pairs
    const int w0   = wid * 2 + r;
    const int a0   = 320 * k2;           // LDS offset of frame 2k2, col 0

    // row start (b*400+w)*2998 + 64k + 2k2 is always EVEN -> 8B-aligned
    // float2 stores everywhere (dwordx2, 512 B/wave-instr in 2 segments).
    float* op = out + ((long)b * WIN_SIZE + w0) * NFRAMES + fr;

    // wave covers rows {w0, w0+1} x 64 frames per pass; 50 passes.
    #pragma unroll 5
    for (int w = w0; w < WIN_SIZE; w += 8) {
        float lwv = lw[w];
        float2 v;
        v.x = lx[swz(a0 + w)]       * lwv;   // frame 2k2
        v.y = lx[swz(a0 + 160 + w)] * lwv;   // frame 2k2+1
        if (ok) *(float2*)op = v;
        op += 8L * NFRAMES;
    }
}

extern "C" void kernel_launch(void* const* d_in, const int* in_sizes, int n_in,
                              void* d_out, int out_size, void* d_ws, size_t ws_size,
                              hipStream_t stream) {
    const float* x      = (const float*)d_in[0];
    const float* window = (const float*)d_in[1];
    // d_in[2] = win_shift scalar (160) — compile-time constant here
    float* out = (float*)d_out;

    window_frame_kernel<<<NBLOCKS, 256, 0, stream>>>(x, window, out);
}